// Round 15
// baseline (846.003 us; speedup 1.0000x reference)
//
#include <hip/hip_runtime.h>
#include <hip/hip_bf16.h>

#define T_TOK 2048
#define DIM   2048
#define NE    8
#define NH    5632

typedef __attribute__((ext_vector_type(4))) float f32x4;
typedef __attribute__((ext_vector_type(8))) short short8;
typedef __attribute__((ext_vector_type(4))) unsigned int u32x4;
typedef __attribute__((ext_vector_type(4))) float float4v;

__device__ inline unsigned short f2bf(float f) {
    unsigned u = __builtin_bit_cast(unsigned, f);
    u += 0x7fffu + ((u >> 16) & 1u);       // round-to-nearest-even
    return (unsigned short)(u >> 16);
}

__device__ __forceinline__ short8 pack8(float4v a, float4v b) {
    short8 o;
    o[0]=(short)f2bf(a[0]); o[1]=(short)f2bf(a[1]); o[2]=(short)f2bf(a[2]); o[3]=(short)f2bf(a[3]);
    o[4]=(short)f2bf(b[0]); o[5]=(short)f2bf(b[1]); o[6]=(short)f2bf(b[2]); o[7]=(short)f2bf(b[3]);
    return o;
}

// truncating fp32->bf16 pack of 8 floats via v_perm_b32 (verified r8, absmax 0.031 ok)
__device__ __forceinline__ short8 cvt8(f32x4 lo, f32x4 hi) {
    u32x4 L = __builtin_bit_cast(u32x4, lo);
    u32x4 H = __builtin_bit_cast(u32x4, hi);
    u32x4 r;
    r[0] = __builtin_amdgcn_perm(L[1], L[0], 0x07060302u);
    r[1] = __builtin_amdgcn_perm(L[3], L[2], 0x07060302u);
    r[2] = __builtin_amdgcn_perm(H[1], H[0], 0x07060302u);
    r[3] = __builtin_amdgcn_perm(H[3], H[2], 0x07060302u);
    return __builtin_bit_cast(short8, r);
}

__device__ __forceinline__ void glds16(const void* g, void* l) {
    __builtin_amdgcn_global_load_lds((const __attribute__((address_space(1))) void*)g,
                                     (__attribute__((address_space(3))) void*)l, 16, 0, 0);
}

// ---------------- fp32 -> bf16 flat convert (fallback path only) ----------------
__global__ void k_cvt(const float* __restrict__ src, unsigned short* __restrict__ dst, int n8) {
    int i = blockIdx.x * blockDim.x + threadIdx.x;
    if (i >= n8) return;
    const float4v* xv = (const float4v*)src;
    ((short8*)dst)[i] = pack8(xv[2 * i], xv[2 * i + 1]);
}

// ---------------- gating + count fused (fp32, one wave per token) ----------------
__global__ void k_gate(const float* __restrict__ x, const float* __restrict__ gw,
                       int* __restrict__ rt_e, float* __restrict__ rt_w, int* __restrict__ cnt) {
    int wid = threadIdx.x >> 6, lane = threadIdx.x & 63;
    int t = blockIdx.x * 4 + wid;
    if (t >= T_TOK) return;
    float acc[NE];
#pragma unroll
    for (int e = 0; e < NE; e++) acc[e] = 0.f;
    const float* xr = x + (size_t)t * DIM;
    for (int d = lane; d < DIM; d += 64) {
        float xv = xr[d];
#pragma unroll
        for (int e = 0; e < NE; e++) acc[e] += xv * gw[e * DIM + d];
    }
#pragma unroll
    for (int e = 0; e < NE; e++) {
        float v = acc[e];
#pragma unroll
        for (int off = 32; off; off >>= 1) v += __shfl_xor(v, off);
        acc[e] = v;
    }
    if (lane == 0) {
        int i0 = 0; float s0 = acc[0];
#pragma unroll
        for (int e = 1; e < NE; e++) if (acc[e] > s0) { s0 = acc[e]; i0 = e; }
        int i1 = -1; float s1 = -1e30f;
#pragma unroll
        for (int e = 0; e < NE; e++) if (e != i0 && acc[e] > s1) { s1 = acc[e]; i1 = e; }
        float w0 = 1.f / (1.f + expf(s1 - s0));
        rt_e[2 * t] = i0; rt_e[2 * t + 1] = i1;
        rt_w[2 * t] = w0; rt_w[2 * t + 1] = 1.f - w0;
        atomicAdd(&cnt[i0], 1);
        atomicAdd(&cnt[i1], 1);
    }
}

// exclusive prefix (slot base) + padded-tile prefix (128-row tiles)
__global__ void k_base(const int* __restrict__ cnt, int* __restrict__ base, int* __restrict__ pb) {
    if (threadIdx.x == 0) {
        int s = 0, p = 0;
        for (int e = 0; e < NE; e++) {
            base[e] = s; pb[e] = p;
            s += cnt[e];
            p += ((cnt[e] + 127) >> 7) << 7;
        }
    }
}

__global__ void k_assign(const int* __restrict__ rt_e, const float* __restrict__ rt_w,
                         const int* __restrict__ base, int* __restrict__ run,
                         int* __restrict__ tok, float* __restrict__ tw,
                         int* __restrict__ slotof) {
    int t = blockIdx.x * blockDim.x + threadIdx.x;
    if (t >= T_TOK) return;
#pragma unroll
    for (int k = 0; k < 2; k++) {
        int e = rt_e[2 * t + k];
        int p = atomicAdd(&run[e], 1);
        int g = base[e] + p;
        tok[g] = t;
        tw[g] = rt_w[2 * t + k];
        slotof[2 * t + k] = g;
    }
}

// ---------------- x gather+convert+pack: [ptile][kt32][kc8][row128][8] ----------------
__global__ void k_xpack(const float* __restrict__ x,
                        const int* __restrict__ cnt, const int* __restrict__ base,
                        const int* __restrict__ pb, const int* __restrict__ tok,
                        unsigned short* __restrict__ xp) {
    int e = blockIdx.z, mt = blockIdx.y, kt = blockIdx.x;
    int c = cnt[e], m0 = mt * 128;
    if (m0 >= c) return;
    int gb = base[e];
    int ptile = (pb[e] >> 7) + mt;
    int lane = threadIdx.x & 63, w = threadIdx.x >> 6;
    int kc = lane & 7;
    unsigned short* db = xp + (size_t)ptile * 262144 + (size_t)kt * 8192;
#pragma unroll
    for (int it = 0; it < 4; ++it) {
        int rloc = it * 32 + w * 8 + (lane >> 3);
        int slot = m0 + rloc;
        int t = tok[gb + (slot < c ? slot : 0)];
        const float* s = x + (size_t)t * DIM + kt * 64 + kc * 8;
        *(short8*)(db + kc * 1024 + rloc * 8) = pack8(*(const float4v*)s, *(const float4v*)(s + 4));
    }
}

// ---------------- combine: y[t] = ye[slot0] + ye[slot1] ----------------
__global__ void k_combine(const float* __restrict__ ye, const int* __restrict__ slotof,
                          float* __restrict__ y) {
    int t = blockIdx.x;
    int s0 = slotof[2 * t], s1 = slotof[2 * t + 1];
    const float4v* a = (const float4v*)(ye + (size_t)s0 * DIM);
    const float4v* b = (const float4v*)(ye + (size_t)s1 * DIM);
    float4v* o = (float4v*)(y + (size_t)t * DIM);
    for (int i = threadIdx.x; i < DIM / 4; i += 256) {
        float4v va = a[i], vb = b[i];
        float4v r;
        r[0] = va[0] + vb[0]; r[1] = va[1] + vb[1];
        r[2] = va[2] + vb[2]; r[3] = va[3] + vb[3];
        o[i] = r;
    }
}

// =====================================================================
// FUSED: GEMM1 (BN=32, 32KB LDS, 5 blocks/CU) + packw2 tail.
// blocks [0,nwg1): h = silu(x@w1^T)*(x@w3^T), nt in [0,176) of 32 cols.
// blocks [nwg1, nwg1+11264): w2 fp32 -> bf16 packed (r9 body).
// =====================================================================
__launch_bounds__(256, 5)
__global__ void k_ffn1p(const unsigned short* __restrict__ xp,
                        const float* __restrict__ w1, const float* __restrict__ w3,
                        const int* __restrict__ cnt, const int* __restrict__ pb,
                        unsigned short* __restrict__ hb, int nwg,
                        const float* __restrict__ w2, unsigned short* __restrict__ w2p) {
    int bid = blockIdx.x;
    if (bid >= nwg) {
        // ---- packw2 body (identical math to round-9's k_packw2) ----
        int pid = bid - nwg;               // 0..11263 = 88*16*8
        int kt = pid % 88;
        int r  = pid / 88;
        int nt2 = r & 15;
        int e  = r >> 4;
        int lane = threadIdx.x & 63, w = threadIdx.x >> 6;
        int kc = lane & 7;
        const float* sb = w2 + (size_t)e * DIM * NH;
        unsigned short* db = w2p + ((size_t)(e * 16 + nt2) * 88 + kt) * 8192;
#pragma unroll
        for (int it = 0; it < 4; ++it) {
            int rloc = it * 32 + w * 8 + (lane >> 3);
            const float* s = sb + (size_t)(nt2 * 128 + rloc) * NH + kt * 64 + kc * 8;
            *(short8*)(db + kc * 1024 + rloc * 8) = pack8(*(const float4v*)s, *(const float4v*)(s + 4));
        }
        return;
    }

    // ---- ffn1 body, BN=32 variant of the r8/r12-verified structure ----
    int swz = (bid & 7) * (nwg >> 3) + (bid >> 3);
    int mt = swz & 15;
    int r2 = swz >> 4;
    int nt = r2 % 176;                     // 32-column tiles
    int e  = r2 / 176;
    int c  = cnt[e];
    int m0 = mt * 128;
    if (m0 >= c) return;
    int ptile = (pb[e] >> 7) + mt;

    __shared__ unsigned short As[8192];   // 16KB: [kc8][row128][8] bf16
    __shared__ float B1f[2048];           // 8KB:  [row32][64 f32], 16B pieces XOR-swizzled by row&15
    __shared__ float B3f[2048];

    int tid = threadIdx.x;
    int lane = tid & 63, w = tid >> 6;
    int wm = w >> 1, wn = w & 1;
    int half = w & 1, wh = w >> 1;
    int p15 = lane & 15, rl0 = lane >> 4;

    const unsigned short* aB = xp + (size_t)ptile * 262144 + half * 512 + lane * 8;
    const float* w1e = w1 + (size_t)(e * NH + nt * 32) * DIM;
    const float* w3e = w3 + (size_t)(e * NH + nt * 32) * DIM;

    f32x4 acc1[4], acc3[4];
#pragma unroll
    for (int i = 0; i < 4; i++) { acc1[i] = (f32x4)0.f; acc3[i] = (f32x4)0.f; }

    for (int kt = 0; kt < 32; ++kt) {
        __syncthreads();
        // A: 4 glds16 per thread (1KB contiguous each per wave)
#pragma unroll
        for (int i = 0; i < 4; i++) {
            int kc = i * 2 + wh;
            glds16(aB + kt * 8192 + kc * 1024, (char*)As + kc * 2048 + half * 1024);
        }
        // B1/B3: per-wave rows [w*8, w*8+8), pre-swizzled 16B pieces (key = rloc&15)
#pragma unroll
        for (int i = 0; i < 2; i++) {
            int rloc = w * 8 + i * 4 + rl0;
            int q    = p15 ^ (rloc & 15);
            glds16(w1e + (size_t)rloc * DIM + kt * 64 + q * 4, (char*)B1f + (w * 8 + i * 4) * 256);
            glds16(w3e + (size_t)rloc * DIM + kt * 64 + q * 4, (char*)B3f + (w * 8 + i * 4) * 256);
        }
        asm volatile("s_waitcnt vmcnt(0)" ::: "memory");
        __syncthreads();
#pragma unroll
        for (int kh = 0; kh < 2; kh++) {
            int kc = kh * 4 + rl0;
            short8 a[4], b1, b3;
#pragma unroll
            for (int mf = 0; mf < 4; mf++) {
                int r = wm * 64 + mf * 16 + p15;
                a[mf] = *(const short8*)(As + kc * 1024 + r * 8);
            }
            {
                int rb = wn * 16 + p15;                      // rb&15 == p15
                const float* rB1 = B1f + rb * 64;
                const float* rB3 = B3f + rb * 64;
                int o0 = ((2 * kc) ^ p15) << 2, o1 = ((2 * kc + 1) ^ p15) << 2;
                b1 = cvt8(*(const f32x4*)(rB1 + o0), *(const f32x4*)(rB1 + o1));
                b3 = cvt8(*(const f32x4*)(rB3 + o0), *(const f32x4*)(rB3 + o1));
            }
#pragma unroll
            for (int mf = 0; mf < 4; mf++) {
                acc1[mf] = __builtin_amdgcn_mfma_f32_16x16x32_bf16(a[mf], b1, acc1[mf], 0, 0, 0);
                acc3[mf] = __builtin_amdgcn_mfma_f32_16x16x32_bf16(a[mf], b3, acc3[mf], 0, 0, 0);
            }
        }
    }

    // epilogue: h -> packed hbufp [ptile][kt_h=nt>>1][kc][row][8]
    unsigned short* hT = hb + ((size_t)ptile * 88 + (nt >> 1)) * 8192;
    int colbase = (nt & 1) * 32 + wn * 16 + p15;             // column within 64-wide kt_h block
#pragma unroll
    for (int mf = 0; mf < 4; mf++)
#pragma unroll
        for (int r = 0; r < 4; r++) {
            int row = wm * 64 + mf * 16 + (rl0 << 2) + r;
            if (m0 + row < c) {
                float a = acc1[mf][r];
                float g = a / (1.f + expf(-a));
                float v = g * acc3[mf][r];
                hT[(colbase >> 3) * 1024 + row * 8 + (colbase & 7)] = f2bf(v);
            }
        }
}

// =====================================================================
// GEMM2: ye[slot] = gate_w * (h @ w2^T). 128Mx128N, BK=64, 4 waves.
// Round-5 verified core; plain coalesced stores to ye (r10/r12).
// =====================================================================
__launch_bounds__(256, 4)
__global__ void k_ffn2(const unsigned short* __restrict__ hb,
                       const unsigned short* __restrict__ w2p,
                       const int* __restrict__ cnt, const int* __restrict__ base,
                       const int* __restrict__ pb,
                       const float* __restrict__ tw,
                       float* __restrict__ ye, int nwg) {
    int bid = blockIdx.x;
    int swz = (bid & 7) * (nwg >> 3) + (bid >> 3);
    int mt = swz & 15;
    int r2 = swz >> 4;
    int nt = r2 & 15;
    int e  = r2 >> 4;
    int c  = cnt[e];
    int m0 = mt * 128;
    if (m0 >= c) return;
    int gb = base[e];
    int ptile = (pb[e] >> 7) + mt;
    int n0 = nt * 128;

    __shared__ unsigned short As[8192];
    __shared__ unsigned short Bs[8192];
    __shared__ float gws[128];

    int tid = threadIdx.x;
    if (tid < 128) {
        int s = m0 + tid;
        gws[tid] = (s < c) ? tw[gb + s] : 0.f;
    }

    int lane = tid & 63, w = tid >> 6;
    int wm = w >> 1, wn = w & 1;
    int half = w & 1, wh = w >> 1;

    const unsigned short* aB = hb  + (size_t)ptile * 720896 + half * 512 + lane * 8;
    const unsigned short* bB = w2p + (size_t)(e * 16 + nt) * 720896 + half * 512 + lane * 8;

    f32x4 acc[4][4];
#pragma unroll
    for (int i = 0; i < 4; i++)
#pragma unroll
        for (int j = 0; j < 4; j++) acc[i][j] = (f32x4)0.f;

    for (int kt = 0; kt < 88; ++kt) {
        __syncthreads();
#pragma unroll
        for (int i = 0; i < 4; i++) {
            int kc = i * 2 + wh;
            glds16(aB + kt * 8192 + kc * 1024, (char*)As + kc * 2048 + half * 1024);
            glds16(bB + kt * 8192 + kc * 1024, (char*)Bs + kc * 2048 + half * 1024);
        }
        asm volatile("s_waitcnt vmcnt(0)" ::: "memory");
        __syncthreads();
#pragma unroll
        for (int kh = 0; kh < 2; kh++) {
            int kc = kh * 4 + (lane >> 4);
            short8 a[4], b[4];
#pragma unroll
            for (int mf = 0; mf < 4; mf++) {
                int r = wm * 64 + mf * 16 + (lane & 15);
                a[mf] = *(const short8*)(As + kc * 1024 + r * 8);
            }
#pragma unroll
            for (int nf = 0; nf < 4; nf++) {
                int rb = wn * 64 + nf * 16 + (lane & 15);
                b[nf] = *(const short8*)(Bs + kc * 1024 + rb * 8);
            }
#pragma unroll
            for (int mf = 0; mf < 4; mf++)
#pragma unroll
                for (int nf = 0; nf < 4; nf++)
                    acc[mf][nf] = __builtin_amdgcn_mfma_f32_16x16x32_bf16(a[mf], b[nf], acc[mf][nf], 0, 0, 0);
        }
    }

#pragma unroll
    for (int mf = 0; mf < 4; mf++)
#pragma unroll
        for (int nf = 0; nf < 4; nf++)
#pragma unroll
            for (int r = 0; r < 4; r++) {
                int row = wm * 64 + mf * 16 + ((lane >> 4) << 2) + r;
                int col = wn * 64 + nf * 16 + (lane & 15);
                if (m0 + row < c) {
                    ye[(size_t)(gb + m0 + row) * DIM + n0 + col] = gws[row] * acc[mf][nf][r];
                }
            }
}

// =====================================================================
// FALLBACK (round-0 style): fp32 weights converted in-loop, atomics
// =====================================================================
__launch_bounds__(256)
__global__ void k_ffn1_fb(const unsigned short* __restrict__ xb,
                          const float* __restrict__ w1, const float* __restrict__ w3,
                          const int* __restrict__ cnt, const int* __restrict__ base,
                          const int* __restrict__ tok, unsigned short* __restrict__ hbuf) {
    int e  = blockIdx.x >> 4;
    int mt = blockIdx.x & 15;
    int c  = cnt[e];
    int m0 = mt * 128;
    if (m0 >= c) return;
    int gb = base[e];
    int n0 = blockIdx.y * 64;

    __shared__ unsigned short As[128 * 64];
    __shared__ unsigned short B1s[64 * 64];
    __shared__ unsigned short B3s[64 * 64];
    __shared__ int toks[128];

    int tid = threadIdx.x;
    if (tid < 128) {
        int s = m0 + tid;
        toks[tid] = (s < c) ? tok[gb + s] : tok[gb];
    }
    int lane = tid & 63, wid = tid >> 6;
    int wm = wid >> 1, wn = wid & 1;

    f32x4 acc1[4][2], acc3[4][2];
#pragma unroll
    for (int i = 0; i < 4; i++)
#pragma unroll
        for (int j = 0; j < 2; j++) { acc1[i][j] = (f32x4)0.f; acc3[i][j] = (f32x4)0.f; }

    const float* W1 = w1 + (size_t)e * NH * DIM + (size_t)n0 * DIM;
    const float* W3 = w3 + (size_t)e * NH * DIM + (size_t)n0 * DIM;

    for (int kt = 0; kt < DIM / 64; ++kt) {
        int k0 = kt * 64;
        __syncthreads();
#pragma unroll
        for (int i = 0; i < 4; i++) {
            int f = i * 256 + tid;
            int row = f >> 3, ch = f & 7;
            u32x4 v = *(const u32x4*)(xb + (size_t)toks[row] * DIM + k0 + ch * 8);
            *(u32x4*)(As + row * 64 + ((ch ^ (row & 7)) << 3)) = v;
        }
#pragma unroll
        for (int i = 0; i < 2; i++) {
            int f = i * 256 + tid;
            int row = f >> 3, ch = f & 7;
            {
                const float* src = W1 + (size_t)row * DIM + k0 + ch * 8;
                *(short8*)(B1s + row * 64 + ((ch ^ (row & 7)) << 3)) =
                    pack8(*(const float4v*)src, *(const float4v*)(src + 4));
            }
            {
                const float* src = W3 + (size_t)row * DIM + k0 + ch * 8;
                *(short8*)(B3s + row * 64 + ((ch ^ (row & 7)) << 3)) =
                    pack8(*(const float4v*)src, *(const float4v*)(src + 4));
            }
        }
        __syncthreads();
#pragma unroll
        for (int kk = 0; kk < 2; kk++) {
            int kch = kk * 4 + (lane >> 4);
            short8 af[4], b1f[2], b3f[2];
#pragma unroll
            for (int mf = 0; mf < 4; mf++) {
                int r = wm * 64 + mf * 16 + (lane & 15);
                af[mf] = *(const short8*)(As + r * 64 + ((kch ^ (r & 7)) << 3));
            }
#pragma unroll
            for (int nf = 0; nf < 2; nf++) {
                int r = wn * 32 + nf * 16 + (lane & 15);
                b1f[nf] = *(const short8*)(B1s + r * 64 + ((kch ^ (r & 7)) << 3));
                b3f[nf] = *(const short8*)(B3s + r * 64 + ((kch ^ (r & 7)) << 3));
            }
#pragma unroll
            for (int mf = 0; mf < 4; mf++)
#pragma unroll
                for (int nf = 0; nf < 2; nf++) {
                    acc1[mf][nf] = __builtin_amdgcn_mfma_f32_16x16x32_bf16(af[mf], b1f[nf], acc1[mf][nf], 0, 0, 0);
                    acc3[mf][nf] = __builtin_amdgcn_mfma_f32_16x16x32_bf16(af[mf], b3f[nf], acc3[mf][nf], 0, 0, 0);
                }
        }
    }
#pragma unroll
    for (int mf = 0; mf < 4; mf++)
#pragma unroll
        for (int nf = 0; nf < 2; nf++)
#pragma unroll
            for (int r = 0; r < 4; r++) {
                int row = wm * 64 + mf * 16 + ((lane >> 4) << 2) + r;
                int col = wn * 32 + nf * 16 + (lane & 15);
                if (m0 + row < c) {
                    float a = acc1[mf][nf][r];
                    float g = a / (1.f + expf(-a));
                    float v = g * acc3[mf][nf][r];
                    hbuf[(size_t)(gb + m0 + row) * NH + n0 + col] = f2bf(v);
                }
            }
}

__launch_bounds__(256)
__global__ void k_ffn2_fb(const unsigned short* __restrict__ hbuf,
                          const float* __restrict__ w2,
                          const int* __restrict__ cnt, const int* __restrict__ base,
                          const int* __restrict__ tok, const float* __restrict__ tw,
                          float* __restrict__ y) {
    int e  = blockIdx.x >> 4;
    int mt = blockIdx.x & 15;
    int c  = cnt[e];
    int m0 = mt * 128;
    if (m0 >= c) return;
    int gb = base[e];
    int n0 = blockIdx.y * 128;

    __shared__ unsigned short As[128 * 64];
    __shared__ unsigned short Bs[128 * 64];
    __shared__ int   toks[128];
    __shared__ float gws[128];

    int tid = threadIdx.x;
    if (tid < 128) {
        int s = m0 + tid;
        toks[tid] = (s < c) ? tok[gb + s] : 0;
        gws[tid]  = (s < c) ? tw[gb + s] : 0.f;
    }
    int lane = tid & 63, wid = tid >> 6;
    int wm = wid >> 1, wn = wid & 1;

    f32x4 acc[4][4];
#pragma unroll
    for (int i = 0; i < 4; i++)
#pragma unroll
        for (int j = 0; j < 4; j++) acc[i][j] = (f32x4)0.f;

    const float* W2 = w2 + (size_t)e * DIM * NH + (size_t)n0 * NH;

    for (int kt = 0; kt < NH / 64; ++kt) {
        int k0 = kt * 64;
        __syncthreads();
#pragma unroll
        for (int i = 0; i < 4; i++) {
            int f = i * 256 + tid;
            int row = f >> 3, ch = f & 7;
            int rr = m0 + row; rr = (rr < c) ? rr : (c - 1);
            u32x4 v = *(const u32x4*)(hbuf + (size_t)(gb + rr) * NH + k0 + ch * 8);
            *(u32x4*)(As + row * 64 + ((ch ^ (row & 7)) << 3)) = v;
        }
#pragma unroll
        for (int i = 0; i < 4; i++) {
            int f = i * 256 + tid;
            int row = f >> 3, ch = f & 7;
            const float* src = W2 + (size_t)row * NH + k0 + ch * 8;
            *(short8*)(Bs + row * 64 + ((ch ^ (row & 7)) << 3)) =
                pack8(*(const float4v*)src, *(const float4v*)(src + 4));
        }
        __syncthreads();
#pragma unroll
        for (int kk = 0; kk < 2; kk++) {
            int kch = kk * 4 + (lane >> 4);
            short8 af[4], bf[4];
#pragma unroll
            for (int mf = 0; mf < 4; mf++) {
                int r = wm * 64 + mf * 16 + (lane & 15);
                af[mf] = *(const short8*)(As + r * 64 + ((kch ^ (r & 7)) << 3));
            }
#pragma unroll
            for (int nf = 0; nf < 4; nf++) {
                int r = wn * 64 + nf * 16 + (lane & 15);
                bf[nf] = *(const short8*)(Bs + r * 64 + ((kch ^ (r & 7)) << 3));
            }
#pragma unroll
            for (int mf = 0; mf < 4; mf++)
#pragma unroll
                for (int nf = 0; nf < 4; nf++)
                    acc[mf][nf] = __builtin_amdgcn_mfma_f32_16x16x32_bf16(af[mf], bf[nf], acc[mf][nf], 0, 0, 0);
        }
    }
#pragma unroll
    for (int mf = 0; mf < 4; mf++)
#pragma unroll
        for (int nf = 0; nf < 4; nf++)
#pragma unroll
            for (int r = 0; r < 4; r++) {
                int row = wm * 64 + mf * 16 + ((lane >> 4) << 2) + r;
                int col = wn * 64 + nf * 16 + (lane & 15);
                if (m0 + row < c) {
                    float v = gws[row] * acc[mf][nf][r];
                    atomicAdd(&y[(size_t)toks[row] * DIM + n0 + col], v);
                }
            }
}

// ---------------- launch ----------------
extern "C" void kernel_launch(void* const* d_in, const int* in_sizes, int n_in,
                              void* d_out, int out_size, void* d_ws, size_t ws_size,
                              hipStream_t stream) {
    const float* x  = (const float*)d_in[0];
    const float* gw = (const float*)d_in[1];
    const float* w1 = (const float*)d_in[2];
    const float* w2 = (const float*)d_in[3];
    const float* w3 = (const float*)d_in[4];
    float* y = (float*)d_out;

    char* ws = (char*)d_ws;
    int*   cnt  = (int*)(ws + 0);
    int*   run  = (int*)(ws + 64);
    int*   basep= (int*)(ws + 128);
    int*   pb   = (int*)(ws + 192);
    int*   tok  = (int*)(ws + 256);
    float* tw   = (float*)(ws + 16640);
    int*   rt_e = (int*)(ws + 33024);
    float* rt_w = (float*)(ws + 49408);
    unsigned short* xp    = (unsigned short*)(ws + 66048);       // 20,971,520 B (also xb in fallback)
    unsigned short* hbufp = (unsigned short*)(ws + 21037568);    // 57,671,680 B (also hbuf flat in fallback)
    unsigned short* w2p   = (unsigned short*)(ws + 78709248);    // 184,549,376 B
    int*   slotof = (int*)(ws + 263258624);                      // 16,384 B
    float* ye     = (float*)(ws + 263275008);                    // 33,554,432 B
    const size_t needed = 296829440ull;

    hipMemsetAsync(ws, 0, 256, stream);

    if (ws_size >= needed) {
        k_gate<<<T_TOK / 4, 256, 0, stream>>>(x, gw, rt_e, rt_w, cnt);
        k_base<<<1, 64, 0, stream>>>(cnt, basep, pb);
        k_assign<<<T_TOK / 256, 256, 0, stream>>>(rt_e, rt_w, basep, run, tok, tw, slotof);
        k_xpack<<<dim3(32, 16, NE), 256, 0, stream>>>(x, cnt, basep, pb, tok, xp);
        int nwg1 = NE * 16 * 176;    // 22528 (BN=32 tiles)
        int nwg2 = NE * 16 * 16;     // 2048
        // fused: ffn1 BN=32 (blocks < nwg1) + packw2 (blocks >= nwg1)
        k_ffn1p<<<nwg1 + 11264, 256, 0, stream>>>(xp, w1, w3, cnt, pb, hbufp, nwg1, w2, w2p);
        k_ffn2<<<nwg2, 256, 0, stream>>>(hbufp, w2p, cnt, basep, pb, tw, ye, nwg2);
        k_combine<<<T_TOK, 256, 0, stream>>>(ye, slotof, y);
    } else {
        hipMemsetAsync(d_out, 0, (size_t)out_size * sizeof(float), stream);
        k_gate<<<T_TOK / 4, 256, 0, stream>>>(x, gw, rt_e, rt_w, cnt);
        k_base<<<1, 64, 0, stream>>>(cnt, basep, pb);
        k_assign<<<T_TOK / 256, 256, 0, stream>>>(rt_e, rt_w, basep, run, tok, tw, (int*)(ws + 49408 + 16384));
        k_cvt<<<(T_TOK * DIM / 8) / 256, 256, 0, stream>>>(x, xp, T_TOK * DIM / 8);
        k_ffn1_fb<<<dim3(NE * 16, NH / 64), 256, 0, stream>>>(xp, w1, w3, cnt, basep, tok, hbufp);
        k_ffn2_fb<<<dim3(NE * 16, DIM / 128), 256, 0, stream>>>(hbufp, w2, cnt, basep, tok, tw, y);
    }
}

// Round 16
// 778.289 us; speedup vs baseline: 1.0870x; 1.0870x over previous
//
#include <hip/hip_runtime.h>
#include <hip/hip_bf16.h>

#define T_TOK 2048
#define DIM   2048
#define NE    8
#define NH    5632

typedef __attribute__((ext_vector_type(4))) float f32x4;
typedef __attribute__((ext_vector_type(8))) short short8;
typedef __attribute__((ext_vector_type(4))) unsigned int u32x4;
typedef __attribute__((ext_vector_type(4))) float float4v;

__device__ inline unsigned short f2bf(float f) {
    unsigned u = __builtin_bit_cast(unsigned, f);
    u += 0x7fffu + ((u >> 16) & 1u);       // round-to-nearest-even
    return (unsigned short)(u >> 16);
}

__device__ __forceinline__ short8 pack8(float4v a, float4v b) {
    short8 o;
    o[0]=(short)f2bf(a[0]); o[1]=(short)f2bf(a[1]); o[2]=(short)f2bf(a[2]); o[3]=(short)f2bf(a[3]);
    o[4]=(short)f2bf(b[0]); o[5]=(short)f2bf(b[1]); o[6]=(short)f2bf(b[2]); o[7]=(short)f2bf(b[3]);
    return o;
}

// truncating fp32->bf16 pack of 8 floats via v_perm_b32 (verified r8, absmax 0.031 ok)
__device__ __forceinline__ short8 cvt8(f32x4 lo, f32x4 hi) {
    u32x4 L = __builtin_bit_cast(u32x4, lo);
    u32x4 H = __builtin_bit_cast(u32x4, hi);
    u32x4 r;
    r[0] = __builtin_amdgcn_perm(L[1], L[0], 0x07060302u);
    r[1] = __builtin_amdgcn_perm(L[3], L[2], 0x07060302u);
    r[2] = __builtin_amdgcn_perm(H[1], H[0], 0x07060302u);
    r[3] = __builtin_amdgcn_perm(H[3], H[2], 0x07060302u);
    return __builtin_bit_cast(short8, r);
}

__device__ __forceinline__ void glds16(const void* g, void* l) {
    __builtin_amdgcn_global_load_lds((const __attribute__((address_space(1))) void*)g,
                                     (__attribute__((address_space(3))) void*)l, 16, 0, 0);
}

// ---------------- fp32 -> bf16 flat convert (fallback path only) ----------------
__global__ void k_cvt(const float* __restrict__ src, unsigned short* __restrict__ dst, int n8) {
    int i = blockIdx.x * blockDim.x + threadIdx.x;
    if (i >= n8) return;
    const float4v* xv = (const float4v*)src;
    ((short8*)dst)[i] = pack8(xv[2 * i], xv[2 * i + 1]);
}

// ---------------- gating + count fused (fp32, one wave per token) ----------------
__global__ void k_gate(const float* __restrict__ x, const float* __restrict__ gw,
                       int* __restrict__ rt_e, float* __restrict__ rt_w, int* __restrict__ cnt) {
    int wid = threadIdx.x >> 6, lane = threadIdx.x & 63;
    int t = blockIdx.x * 4 + wid;
    if (t >= T_TOK) return;
    float acc[NE];
#pragma unroll
    for (int e = 0; e < NE; e++) acc[e] = 0.f;
    const float* xr = x + (size_t)t * DIM;
    for (int d = lane; d < DIM; d += 64) {
        float xv = xr[d];
#pragma unroll
        for (int e = 0; e < NE; e++) acc[e] += xv * gw[e * DIM + d];
    }
#pragma unroll
    for (int e = 0; e < NE; e++) {
        float v = acc[e];
#pragma unroll
        for (int off = 32; off; off >>= 1) v += __shfl_xor(v, off);
        acc[e] = v;
    }
    if (lane == 0) {
        int i0 = 0; float s0 = acc[0];
#pragma unroll
        for (int e = 1; e < NE; e++) if (acc[e] > s0) { s0 = acc[e]; i0 = e; }
        int i1 = -1; float s1 = -1e30f;
#pragma unroll
        for (int e = 0; e < NE; e++) if (e != i0 && acc[e] > s1) { s1 = acc[e]; i1 = e; }
        float w0 = 1.f / (1.f + expf(s1 - s0));
        rt_e[2 * t] = i0; rt_e[2 * t + 1] = i1;
        rt_w[2 * t] = w0; rt_w[2 * t + 1] = 1.f - w0;
        atomicAdd(&cnt[i0], 1);
        atomicAdd(&cnt[i1], 1);
    }
}

// exclusive prefix (slot base) + padded-tile prefix (128-row tiles)
__global__ void k_base(const int* __restrict__ cnt, int* __restrict__ base, int* __restrict__ pb) {
    if (threadIdx.x == 0) {
        int s = 0, p = 0;
        for (int e = 0; e < NE; e++) {
            base[e] = s; pb[e] = p;
            s += cnt[e];
            p += ((cnt[e] + 127) >> 7) << 7;
        }
    }
}

__global__ void k_assign(const int* __restrict__ rt_e, const float* __restrict__ rt_w,
                         const int* __restrict__ base, int* __restrict__ run,
                         int* __restrict__ tok, float* __restrict__ tw,
                         int* __restrict__ slotof) {
    int t = blockIdx.x * blockDim.x + threadIdx.x;
    if (t >= T_TOK) return;
#pragma unroll
    for (int k = 0; k < 2; k++) {
        int e = rt_e[2 * t + k];
        int p = atomicAdd(&run[e], 1);
        int g = base[e] + p;
        tok[g] = t;
        tw[g] = rt_w[2 * t + k];
        slotof[2 * t + k] = g;
    }
}

// ---------------- x gather+convert+pack: [ptile][kt32][kc8][row128][8] ----------------
__global__ void k_xpack(const float* __restrict__ x,
                        const int* __restrict__ cnt, const int* __restrict__ base,
                        const int* __restrict__ pb, const int* __restrict__ tok,
                        unsigned short* __restrict__ xp) {
    int e = blockIdx.z, mt = blockIdx.y, kt = blockIdx.x;
    int c = cnt[e], m0 = mt * 128;
    if (m0 >= c) return;
    int gb = base[e];
    int ptile = (pb[e] >> 7) + mt;
    int lane = threadIdx.x & 63, w = threadIdx.x >> 6;
    int kc = lane & 7;
    unsigned short* db = xp + (size_t)ptile * 262144 + (size_t)kt * 8192;
#pragma unroll
    for (int it = 0; it < 4; ++it) {
        int rloc = it * 32 + w * 8 + (lane >> 3);
        int slot = m0 + rloc;
        int t = tok[gb + (slot < c ? slot : 0)];
        const float* s = x + (size_t)t * DIM + kt * 64 + kc * 8;
        *(short8*)(db + kc * 1024 + rloc * 8) = pack8(*(const float4v*)s, *(const float4v*)(s + 4));
    }
}

// ---------------- combine: y[t] = ye[slot0] + ye[slot1] ----------------
__global__ void k_combine(const float* __restrict__ ye, const int* __restrict__ slotof,
                          float* __restrict__ y) {
    int t = blockIdx.x;
    int s0 = slotof[2 * t], s1 = slotof[2 * t + 1];
    const float4v* a = (const float4v*)(ye + (size_t)s0 * DIM);
    const float4v* b = (const float4v*)(ye + (size_t)s1 * DIM);
    float4v* o = (float4v*)(y + (size_t)t * DIM);
    for (int i = threadIdx.x; i < DIM / 4; i += 256) {
        float4v va = a[i], vb = b[i];
        float4v r;
        r[0] = va[0] + vb[0]; r[1] = va[1] + vb[1];
        r[2] = va[2] + vb[2]; r[3] = va[3] + vb[3];
        o[i] = r;
    }
}

// =====================================================================
// FUSED: GEMM1 + packw2 (round-12 verified, best config 779 us).
// blocks [0,nwg1): h = silu(x@w1^T)*(x@w3^T) — round-8/9 verified body.
// blocks [nwg1, nwg1+11264): w2 fp32 -> bf16 packed (pure BW, fills
// ffn1's latency bubbles; stream order makes w2p ready before k_ffn2).
// =====================================================================
__launch_bounds__(256, 3)
__global__ void k_ffn1p(const unsigned short* __restrict__ xp,
                        const float* __restrict__ w1, const float* __restrict__ w3,
                        const int* __restrict__ cnt, const int* __restrict__ pb,
                        unsigned short* __restrict__ hb, int nwg,
                        const float* __restrict__ w2, unsigned short* __restrict__ w2p) {
    int bid = blockIdx.x;
    if (bid >= nwg) {
        // ---- packw2 body (identical math to round-9's k_packw2) ----
        int pid = bid - nwg;               // 0..11263 = 88*16*8
        int kt = pid % 88;
        int r  = pid / 88;
        int nt = r & 15;
        int e  = r >> 4;
        int lane = threadIdx.x & 63, w = threadIdx.x >> 6;
        int kc = lane & 7;
        const float* sb = w2 + (size_t)e * DIM * NH;
        unsigned short* db = w2p + ((size_t)(e * 16 + nt) * 88 + kt) * 8192;
#pragma unroll
        for (int it = 0; it < 4; ++it) {
            int rloc = it * 32 + w * 8 + (lane >> 3);
            const float* s = sb + (size_t)(nt * 128 + rloc) * NH + kt * 64 + kc * 8;
            *(short8*)(db + kc * 1024 + rloc * 8) = pack8(*(const float4v*)s, *(const float4v*)(s + 4));
        }
        return;
    }

    // ---- ffn1 body (round-8/9 verified) ----
    int swz = (bid & 7) * (nwg >> 3) + (bid >> 3);
    int mt = swz & 15;
    int r2 = swz >> 4;
    int nt = r2 % 88;
    int e  = r2 / 88;
    int c  = cnt[e];
    int m0 = mt * 128;
    if (m0 >= c) return;
    int ptile = (pb[e] >> 7) + mt;

    __shared__ unsigned short As[8192];   // 16KB: [kc8][row128][8] bf16
    __shared__ float B1f[4096];           // 16KB: [row64][64 f32], 16B pieces XOR-swizzled by row&15
    __shared__ float B3f[4096];

    int tid = threadIdx.x;
    int lane = tid & 63, w = tid >> 6;
    int wm = w >> 1, wn = w & 1;
    int half = w & 1, wh = w >> 1;
    int p15 = lane & 15, rl0 = lane >> 4;

    const unsigned short* aB = xp + (size_t)ptile * 262144 + half * 512 + lane * 8;
    const float* w1e = w1 + (size_t)(e * NH + nt * 64) * DIM;
    const float* w3e = w3 + (size_t)(e * NH + nt * 64) * DIM;

    f32x4 acc1[4][2], acc3[4][2];
#pragma unroll
    for (int i = 0; i < 4; i++)
#pragma unroll
        for (int j = 0; j < 2; j++) { acc1[i][j] = (f32x4)0.f; acc3[i][j] = (f32x4)0.f; }

    for (int kt = 0; kt < 32; ++kt) {
        __syncthreads();
#pragma unroll
        for (int i = 0; i < 4; i++) {
            int kc = i * 2 + wh;
            glds16(aB + kt * 8192 + kc * 1024, (char*)As + kc * 2048 + half * 1024);
        }
#pragma unroll
        for (int i = 0; i < 4; i++) {
            int rloc = w * 16 + i * 4 + rl0;
            int q    = p15 ^ ((i * 4 + rl0) & 15);
            glds16(w1e + (size_t)rloc * DIM + kt * 64 + q * 4, (char*)B1f + (w * 16 + i * 4) * 256);
            glds16(w3e + (size_t)rloc * DIM + kt * 64 + q * 4, (char*)B3f + (w * 16 + i * 4) * 256);
        }
        asm volatile("s_waitcnt vmcnt(0)" ::: "memory");
        __syncthreads();
#pragma unroll
        for (int kh = 0; kh < 2; kh++) {
            int kc = kh * 4 + rl0;
            short8 a[4], b1[2], b3[2];
#pragma unroll
            for (int mf = 0; mf < 4; mf++) {
                int r = wm * 64 + mf * 16 + p15;
                a[mf] = *(const short8*)(As + kc * 1024 + r * 8);
            }
#pragma unroll
            for (int nf = 0; nf < 2; nf++) {
                int rb = wn * 32 + nf * 16 + p15;            // rb&15 == p15
                const float* rB1 = B1f + rb * 64;
                const float* rB3 = B3f + rb * 64;
                int o0 = ((2 * kc) ^ p15) << 2, o1 = ((2 * kc + 1) ^ p15) << 2;
                b1[nf] = cvt8(*(const f32x4*)(rB1 + o0), *(const f32x4*)(rB1 + o1));
                b3[nf] = cvt8(*(const f32x4*)(rB3 + o0), *(const f32x4*)(rB3 + o1));
            }
#pragma unroll
            for (int mf = 0; mf < 4; mf++)
#pragma unroll
                for (int nf = 0; nf < 2; nf++) {
                    acc1[mf][nf] = __builtin_amdgcn_mfma_f32_16x16x32_bf16(a[mf], b1[nf], acc1[mf][nf], 0, 0, 0);
                    acc3[mf][nf] = __builtin_amdgcn_mfma_f32_16x16x32_bf16(a[mf], b3[nf], acc3[mf][nf], 0, 0, 0);
                }
        }
    }

    // epilogue: h -> packed hbufp [ptile][kt_h=nt][kc][row][8]
    unsigned short* hT = hb + ((size_t)ptile * 88 + nt) * 8192;
#pragma unroll
    for (int mf = 0; mf < 4; mf++)
#pragma unroll
        for (int nf = 0; nf < 2; nf++)
#pragma unroll
            for (int r = 0; r < 4; r++) {
                int row = wm * 64 + mf * 16 + (rl0 << 2) + r;
                int col = wn * 32 + nf * 16 + p15;
                if (m0 + row < c) {
                    float a = acc1[mf][nf][r];
                    float g = a / (1.f + expf(-a));
                    float v = g * acc3[mf][nf][r];
                    hT[(col >> 3) * 1024 + row * 8 + (col & 7)] = f2bf(v);
                }
            }
}

// =====================================================================
// GEMM2: ye[slot] = gate_w * (h @ w2^T). 128Mx128N, BK=64, 4 waves.
// Round-5 verified core; plain coalesced stores to ye (r10/r12).
// =====================================================================
__launch_bounds__(256, 4)
__global__ void k_ffn2(const unsigned short* __restrict__ hb,
                       const unsigned short* __restrict__ w2p,
                       const int* __restrict__ cnt, const int* __restrict__ base,
                       const int* __restrict__ pb,
                       const float* __restrict__ tw,
                       float* __restrict__ ye, int nwg) {
    int bid = blockIdx.x;
    int swz = (bid & 7) * (nwg >> 3) + (bid >> 3);
    int mt = swz & 15;
    int r2 = swz >> 4;
    int nt = r2 & 15;
    int e  = r2 >> 4;
    int c  = cnt[e];
    int m0 = mt * 128;
    if (m0 >= c) return;
    int gb = base[e];
    int ptile = (pb[e] >> 7) + mt;
    int n0 = nt * 128;

    __shared__ unsigned short As[8192];
    __shared__ unsigned short Bs[8192];
    __shared__ float gws[128];

    int tid = threadIdx.x;
    if (tid < 128) {
        int s = m0 + tid;
        gws[tid] = (s < c) ? tw[gb + s] : 0.f;
    }

    int lane = tid & 63, w = tid >> 6;
    int wm = w >> 1, wn = w & 1;
    int half = w & 1, wh = w >> 1;

    const unsigned short* aB = hb  + (size_t)ptile * 720896 + half * 512 + lane * 8;
    const unsigned short* bB = w2p + (size_t)(e * 16 + nt) * 720896 + half * 512 + lane * 8;

    f32x4 acc[4][4];
#pragma unroll
    for (int i = 0; i < 4; i++)
#pragma unroll
        for (int j = 0; j < 4; j++) acc[i][j] = (f32x4)0.f;

    for (int kt = 0; kt < 88; ++kt) {
        __syncthreads();
#pragma unroll
        for (int i = 0; i < 4; i++) {
            int kc = i * 2 + wh;
            glds16(aB + kt * 8192 + kc * 1024, (char*)As + kc * 2048 + half * 1024);
            glds16(bB + kt * 8192 + kc * 1024, (char*)Bs + kc * 2048 + half * 1024);
        }
        asm volatile("s_waitcnt vmcnt(0)" ::: "memory");
        __syncthreads();
#pragma unroll
        for (int kh = 0; kh < 2; kh++) {
            int kc = kh * 4 + (lane >> 4);
            short8 a[4], b[4];
#pragma unroll
            for (int mf = 0; mf < 4; mf++) {
                int r = wm * 64 + mf * 16 + (lane & 15);
                a[mf] = *(const short8*)(As + kc * 1024 + r * 8);
            }
#pragma unroll
            for (int nf = 0; nf < 4; nf++) {
                int rb = wn * 64 + nf * 16 + (lane & 15);
                b[nf] = *(const short8*)(Bs + kc * 1024 + rb * 8);
            }
#pragma unroll
            for (int mf = 0; mf < 4; mf++)
#pragma unroll
                for (int nf = 0; nf < 4; nf++)
                    acc[mf][nf] = __builtin_amdgcn_mfma_f32_16x16x32_bf16(a[mf], b[nf], acc[mf][nf], 0, 0, 0);
        }
    }

#pragma unroll
    for (int mf = 0; mf < 4; mf++)
#pragma unroll
        for (int nf = 0; nf < 4; nf++)
#pragma unroll
            for (int r = 0; r < 4; r++) {
                int row = wm * 64 + mf * 16 + ((lane >> 4) << 2) + r;
                int col = wn * 64 + nf * 16 + (lane & 15);
                if (m0 + row < c) {
                    ye[(size_t)(gb + m0 + row) * DIM + n0 + col] = gws[row] * acc[mf][nf][r];
                }
            }
}

// =====================================================================
// FALLBACK (round-0 style): fp32 weights converted in-loop, atomics
// =====================================================================
__launch_bounds__(256)
__global__ void k_ffn1_fb(const unsigned short* __restrict__ xb,
                          const float* __restrict__ w1, const float* __restrict__ w3,
                          const int* __restrict__ cnt, const int* __restrict__ base,
                          const int* __restrict__ tok, unsigned short* __restrict__ hbuf) {
    int e  = blockIdx.x >> 4;
    int mt = blockIdx.x & 15;
    int c  = cnt[e];
    int m0 = mt * 128;
    if (m0 >= c) return;
    int gb = base[e];
    int n0 = blockIdx.y * 64;

    __shared__ unsigned short As[128 * 64];
    __shared__ unsigned short B1s[64 * 64];
    __shared__ unsigned short B3s[64 * 64];
    __shared__ int toks[128];

    int tid = threadIdx.x;
    if (tid < 128) {
        int s = m0 + tid;
        toks[tid] = (s < c) ? tok[gb + s] : tok[gb];
    }
    int lane = tid & 63, wid = tid >> 6;
    int wm = wid >> 1, wn = wid & 1;

    f32x4 acc1[4][2], acc3[4][2];
#pragma unroll
    for (int i = 0; i < 4; i++)
#pragma unroll
        for (int j = 0; j < 2; j++) { acc1[i][j] = (f32x4)0.f; acc3[i][j] = (f32x4)0.f; }

    const float* W1 = w1 + (size_t)e * NH * DIM + (size_t)n0 * DIM;
    const float* W3 = w3 + (size_t)e * NH * DIM + (size_t)n0 * DIM;

    for (int kt = 0; kt < DIM / 64; ++kt) {
        int k0 = kt * 64;
        __syncthreads();
#pragma unroll
        for (int i = 0; i < 4; i++) {
            int f = i * 256 + tid;
            int row = f >> 3, ch = f & 7;
            u32x4 v = *(const u32x4*)(xb + (size_t)toks[row] * DIM + k0 + ch * 8);
            *(u32x4*)(As + row * 64 + ((ch ^ (row & 7)) << 3)) = v;
        }
#pragma unroll
        for (int i = 0; i < 2; i++) {
            int f = i * 256 + tid;
            int row = f >> 3, ch = f & 7;
            {
                const float* src = W1 + (size_t)row * DIM + k0 + ch * 8;
                *(short8*)(B1s + row * 64 + ((ch ^ (row & 7)) << 3)) =
                    pack8(*(const float4v*)src, *(const float4v*)(src + 4));
            }
            {
                const float* src = W3 + (size_t)row * DIM + k0 + ch * 8;
                *(short8*)(B3s + row * 64 + ((ch ^ (row & 7)) << 3)) =
                    pack8(*(const float4v*)src, *(const float4v*)(src + 4));
            }
        }
        __syncthreads();
#pragma unroll
        for (int kk = 0; kk < 2; kk++) {
            int kch = kk * 4 + (lane >> 4);
            short8 af[4], b1f[2], b3f[2];
#pragma unroll
            for (int mf = 0; mf < 4; mf++) {
                int r = wm * 64 + mf * 16 + (lane & 15);
                af[mf] = *(const short8*)(As + r * 64 + ((kch ^ (r & 7)) << 3));
            }
#pragma unroll
            for (int nf = 0; nf < 2; nf++) {
                int r = wn * 32 + nf * 16 + (lane & 15);
                b1f[nf] = *(const short8*)(B1s + r * 64 + ((kch ^ (r & 7)) << 3));
                b3f[nf] = *(const short8*)(B3s + r * 64 + ((kch ^ (r & 7)) << 3));
            }
#pragma unroll
            for (int mf = 0; mf < 4; mf++)
#pragma unroll
                for (int nf = 0; nf < 2; nf++) {
                    acc1[mf][nf] = __builtin_amdgcn_mfma_f32_16x16x32_bf16(af[mf], b1f[nf], acc1[mf][nf], 0, 0, 0);
                    acc3[mf][nf] = __builtin_amdgcn_mfma_f32_16x16x32_bf16(af[mf], b3f[nf], acc3[mf][nf], 0, 0, 0);
                }
        }
    }
#pragma unroll
    for (int mf = 0; mf < 4; mf++)
#pragma unroll
        for (int nf = 0; nf < 2; nf++)
#pragma unroll
            for (int r = 0; r < 4; r++) {
                int row = wm * 64 + mf * 16 + ((lane >> 4) << 2) + r;
                int col = wn * 32 + nf * 16 + (lane & 15);
                if (m0 + row < c) {
                    float a = acc1[mf][nf][r];
                    float g = a / (1.f + expf(-a));
                    float v = g * acc3[mf][nf][r];
                    hbuf[(size_t)(gb + m0 + row) * NH + n0 + col] = f2bf(v);
                }
            }
}

__launch_bounds__(256)
__global__ void k_ffn2_fb(const unsigned short* __restrict__ hbuf,
                          const float* __restrict__ w2,
                          const int* __restrict__ cnt, const int* __restrict__ base,
                          const int* __restrict__ tok, const float* __restrict__ tw,
                          float* __restrict__ y) {
    int e  = blockIdx.x >> 4;
    int mt = blockIdx.x & 15;
    int c  = cnt[e];
    int m0 = mt * 128;
    if (m0 >= c) return;
    int gb = base[e];
    int n0 = blockIdx.y * 128;

    __shared__ unsigned short As[128 * 64];
    __shared__ unsigned short Bs[128 * 64];
    __shared__ int   toks[128];
    __shared__ float gws[128];

    int tid = threadIdx.x;
    if (tid < 128) {
        int s = m0 + tid;
        toks[tid] = (s < c) ? tok[gb + s] : 0;
        gws[tid]  = (s < c) ? tw[gb + s] : 0.f;
    }
    int lane = tid & 63, wid = tid >> 6;
    int wm = wid >> 1, wn = wid & 1;

    f32x4 acc[4][4];
#pragma unroll
    for (int i = 0; i < 4; i++)
#pragma unroll
        for (int j = 0; j < 4; j++) acc[i][j] = (f32x4)0.f;

    const float* W2 = w2 + (size_t)e * DIM * NH + (size_t)n0 * NH;

    for (int kt = 0; kt < NH / 64; ++kt) {
        int k0 = kt * 64;
        __syncthreads();
#pragma unroll
        for (int i = 0; i < 4; i++) {
            int f = i * 256 + tid;
            int row = f >> 3, ch = f & 7;
            int rr = m0 + row; rr = (rr < c) ? rr : (c - 1);
            u32x4 v = *(const u32x4*)(hbuf + (size_t)(gb + rr) * NH + k0 + ch * 8);
            *(u32x4*)(As + row * 64 + ((ch ^ (row & 7)) << 3)) = v;
        }
#pragma unroll
        for (int i = 0; i < 4; i++) {
            int f = i * 256 + tid;
            int row = f >> 3, ch = f & 7;
            const float* src = W2 + (size_t)row * NH + k0 + ch * 8;
            *(short8*)(Bs + row * 64 + ((ch ^ (row & 7)) << 3)) =
                pack8(*(const float4v*)src, *(const float4v*)(src + 4));
        }
        __syncthreads();
#pragma unroll
        for (int kk = 0; kk < 2; kk++) {
            int kch = kk * 4 + (lane >> 4);
            short8 af[4], bf[4];
#pragma unroll
            for (int mf = 0; mf < 4; mf++) {
                int r = wm * 64 + mf * 16 + (lane & 15);
                af[mf] = *(const short8*)(As + r * 64 + ((kch ^ (r & 7)) << 3));
            }
#pragma unroll
            for (int nf = 0; nf < 4; nf++) {
                int r = wn * 64 + nf * 16 + (lane & 15);
                bf[nf] = *(const short8*)(Bs + r * 64 + ((kch ^ (r & 7)) << 3));
            }
#pragma unroll
            for (int mf = 0; mf < 4; mf++)
#pragma unroll
                for (int nf = 0; nf < 4; nf++)
                    acc[mf][nf] = __builtin_amdgcn_mfma_f32_16x16x32_bf16(af[mf], bf[nf], acc[mf][nf], 0, 0, 0);
        }
    }
#pragma unroll
    for (int mf = 0; mf < 4; mf++)
#pragma unroll
        for (int nf = 0; nf < 4; nf++)
#pragma unroll
            for (int r = 0; r < 4; r++) {
                int row = wm * 64 + mf * 16 + ((lane >> 4) << 2) + r;
                int col = wn * 64 + nf * 16 + (lane & 15);
                if (m0 + row < c) {
                    float v = gws[row] * acc[mf][nf][r];
                    atomicAdd(&y[(size_t)toks[row] * DIM + n0 + col], v);
                }
            }
}

// ---------------- launch ----------------
extern "C" void kernel_launch(void* const* d_in, const int* in_sizes, int n_in,
                              void* d_out, int out_size, void* d_ws, size_t ws_size,
                              hipStream_t stream) {
    const float* x  = (const float*)d_in[0];
    const float* gw = (const float*)d_in[1];
    const float* w1 = (const float*)d_in[2];
    const float* w2 = (const float*)d_in[3];
    const float* w3 = (const float*)d_in[4];
    float* y = (float*)d_out;

    char* ws = (char*)d_ws;
    int*   cnt  = (int*)(ws + 0);
    int*   run  = (int*)(ws + 64);
    int*   basep= (int*)(ws + 128);
    int*   pb   = (int*)(ws + 192);
    int*   tok  = (int*)(ws + 256);
    float* tw   = (float*)(ws + 16640);
    int*   rt_e = (int*)(ws + 33024);
    float* rt_w = (float*)(ws + 49408);
    unsigned short* xp    = (unsigned short*)(ws + 66048);       // 20,971,520 B (also xb in fallback)
    unsigned short* hbufp = (unsigned short*)(ws + 21037568);    // 57,671,680 B (also hbuf flat in fallback)
    unsigned short* w2p   = (unsigned short*)(ws + 78709248);    // 184,549,376 B
    int*   slotof = (int*)(ws + 263258624);                      // 16,384 B
    float* ye     = (float*)(ws + 263275008);                    // 33,554,432 B
    const size_t needed = 296829440ull;

    hipMemsetAsync(ws, 0, 256, stream);

    if (ws_size >= needed) {
        k_gate<<<T_TOK / 4, 256, 0, stream>>>(x, gw, rt_e, rt_w, cnt);
        k_base<<<1, 64, 0, stream>>>(cnt, basep, pb);
        k_assign<<<T_TOK / 256, 256, 0, stream>>>(rt_e, rt_w, basep, run, tok, tw, slotof);
        k_xpack<<<dim3(32, 16, NE), 256, 0, stream>>>(x, cnt, basep, pb, tok, xp);
        int nwg1 = NE * 16 * 88;     // 11264
        int nwg2 = NE * 16 * 16;     // 2048
        // fused: ffn1 (blocks < nwg1) + packw2 (blocks >= nwg1)
        k_ffn1p<<<nwg1 + 11264, 256, 0, stream>>>(xp, w1, w3, cnt, pb, hbufp, nwg1, w2, w2p);
        k_ffn2<<<nwg2, 256, 0, stream>>>(hbufp, w2p, cnt, basep, pb, tw, ye, nwg2);
        k_combine<<<T_TOK, 256, 0, stream>>>(ye, slotof, y);
    } else {
        hipMemsetAsync(d_out, 0, (size_t)out_size * sizeof(float), stream);
        k_gate<<<T_TOK / 4, 256, 0, stream>>>(x, gw, rt_e, rt_w, cnt);
        k_base<<<1, 64, 0, stream>>>(cnt, basep, pb);
        k_assign<<<T_TOK / 256, 256, 0, stream>>>(rt_e, rt_w, basep, run, tok, tw, (int*)(ws + 49408 + 16384));
        k_cvt<<<(T_TOK * DIM / 8) / 256, 256, 0, stream>>>(x, xp, T_TOK * DIM / 8);
        k_ffn1_fb<<<dim3(NE * 16, NH / 64), 256, 0, stream>>>(xp, w1, w3, cnt, basep, tok, hbufp);
        k_ffn2_fb<<<dim3(NE * 16, DIM / 128), 256, 0, stream>>>(hbufp, w2, cnt, basep, tok, tw, y);
    }
}